// Round 1
// baseline (366.818 us; speedup 1.0000x reference)
//
#include <hip/hip_runtime.h>

using short8 = __attribute__((ext_vector_type(8))) short;
using f32x4  = __attribute__((ext_vector_type(4))) float;

#define LDSX 132   // f32 row stride for x/out tile (pad 4 dwords)
#define LDSB 136   // bf16 row stride (pad 8 shorts = 16B)
#define PK_CW1 0
#define PK_CW2 16384
#define PK_DW1 32768
#define PK_DW2 49152
#define PK_FW1 65536
#define PK_FW2 98304
#define SMEM_BYTES 69120

__device__ __forceinline__ short f2bf(float f) {
  unsigned u = __builtin_bit_cast(unsigned, f);
  u += 0x7FFFu + ((u >> 16) & 1u);   // round-to-nearest-even
  return (short)(u >> 16);
}

__device__ __forceinline__ float gelu_f(float x) {
  // tanh-form GELU, overflow-safe tanh via exp; max |err| vs erf-GELU ~3e-3
  float u2 = 1.5957691216057308f * (x + 0.044715f * x * x * x); // 2*sqrt(2/pi)*(...)
  float t = 1.0f - 2.0f / (__expf(u2) + 1.0f);
  return 0.5f * x * (1.0f + t);
}

__device__ __forceinline__ f32x4 mfma16(short8 a, short8 b, f32x4 c) {
  return __builtin_amdgcn_mfma_f32_16x16x32_bf16(a, b, c, 0, 0, 0);
}

// Pre-pack all weights into fragment-major bf16:
// packed[fb*512 + lane*8 + j] = bf16(W[kk*32 + (lane>>4)*8 + j][nt*16 + (lane&15)])
// fb = kk*(N/16) + nt.  One thread = one lane-fragment (8 elems).
__global__ void pack_weights_k(const float* __restrict__ cW1, const float* __restrict__ cW2,
                               const float* __restrict__ dW1, const float* __restrict__ dW2,
                               const float* __restrict__ fW1, const float* __restrict__ fW2,
                               short* __restrict__ pk) {
  int fid  = blockIdx.x * 256 + threadIdx.x;   // 0..16383
  int lane = fid & 63;
  int fbg  = fid >> 6;                         // 0..255
  const float* W; int N; int fb;
  if (fbg < 32)       { W = cW1; N = 128; fb = fbg; }
  else if (fbg < 64)  { W = cW2; N = 128; fb = fbg - 32; }
  else if (fbg < 96)  { W = dW1; N = 128; fb = fbg - 64; }
  else if (fbg < 128) { W = dW2; N = 128; fb = fbg - 96; }
  else if (fbg < 192) { W = fW1; N = 256; fb = fbg - 128; }
  else                { W = fW2; N = 128; fb = fbg - 192; }
  int nt = fb % (N >> 4);
  int kk = fb / (N >> 4);
  int row0 = kk * 32 + (lane >> 4) * 8;
  int col  = nt * 16 + (lane & 15);
  short8 v;
  #pragma unroll
  for (int j = 0; j < 8; ++j) v[j] = f2bf(W[(row0 + j) * N + col]);
  *(short8*)&pk[fbg * 512 + lane * 8] = v;
}

__global__ __launch_bounds__(256, 2)
void hemi_fused_k(const float* __restrict__ x,
                  const float* __restrict__ ln_g, const float* __restrict__ ln_b,
                  const float* __restrict__ c_b1, const float* __restrict__ c_b2,
                  const float* __restrict__ d_b1, const float* __restrict__ d_b2,
                  const float* __restrict__ f_b1, const float* __restrict__ f_b2,
                  const short* __restrict__ pk,
                  float* __restrict__ out) {
  extern __shared__ char smem[];
  float* xs = (float*)smem;                        // [64][LDSX] f32 : x, later out
  short* r1 = (short*)(smem + 64 * LDSX * 4);      // cmn[32][LDSB]+dif[32][LDSB]; later hf1[64][LDSB]
  short* r2 = r1 + 2 * 32 * LDSB;                  // h1c[32][LDSB]+h1d[32][LDSB]; later h2[64][LDSB]
  float* smu = (float*)(r2 + 2 * 32 * LDSB);       // [64]
  float* srs = smu + 64;                           // [64]

  const int t = threadIdx.x;
  const size_t base = (size_t)blockIdx.x * 8192;   // (b,t) tile: 64 rows x 128

  // ---------------- Phase A: coalesced load x -> LDS, LN stats from registers
  {
    const float4* xg = (const float4*)(x + base);
    float s[8], q[8];
    #pragma unroll
    for (int i = 0; i < 8; ++i) {
      float4 a = xg[t + 256 * i];
      int row = (t >> 5) + 8 * i;                  // thread holds chunk (t&31) of 8 rows
      *(float4*)&xs[row * LDSX + (t & 31) * 4] = a;
      s[i] = a.x + a.y + a.z + a.w;
      q[i] = a.x * a.x + a.y * a.y + a.z * a.z + a.w * a.w;
    }
    #pragma unroll
    for (int m = 1; m <= 16; m <<= 1) {            // butterfly within 32-lane half
      #pragma unroll
      for (int i = 0; i < 8; ++i) {
        s[i] += __shfl_xor(s[i], m);
        q[i] += __shfl_xor(q[i], m);
      }
    }
    if ((t & 31) == 0) {
      #pragma unroll
      for (int i = 0; i < 8; ++i) {
        int row = (t >> 5) + 8 * i;
        float mu = s[i] * (1.0f / 128.0f);
        float var = q[i] * (1.0f / 128.0f) - mu * mu;
        smu[row] = mu;
        srs[row] = rsqrtf(var + 1e-5f);
      }
    }
  }
  __syncthreads();

  // ---------------- Phase B: LN + pair -> common/diff (bf16, LDS)
  {
    short* cmn = r1;
    short* dif = r1 + 32 * LDSB;
    int j = t & 31, seg = t >> 5;                  // pair j, 16-col segment
    float mu_e = smu[2 * j], rs_e = srs[2 * j];
    float mu_o = smu[2 * j + 1], rs_o = srs[2 * j + 1];
    float xe[16], xo[16];
    #pragma unroll
    for (int u4 = 0; u4 < 4; ++u4) {
      float4 a = *(const float4*)&xs[(2 * j) * LDSX + seg * 16 + 4 * u4];
      float4 b = *(const float4*)&xs[(2 * j + 1) * LDSX + seg * 16 + 4 * u4];
      xe[4*u4+0]=a.x; xe[4*u4+1]=a.y; xe[4*u4+2]=a.z; xe[4*u4+3]=a.w;
      xo[4*u4+0]=b.x; xo[4*u4+1]=b.y; xo[4*u4+2]=b.z; xo[4*u4+3]=b.w;
    }
    #pragma unroll
    for (int h = 0; h < 2; ++h) {
      short8 cv, dv;
      #pragma unroll
      for (int u = 0; u < 8; ++u) {
        int c = seg * 16 + h * 8 + u;
        float g = ln_g[c], b = ln_b[c];
        float he = (xe[h * 8 + u] - mu_e) * rs_e * g + b;
        float ho = (xo[h * 8 + u] - mu_o) * rs_o * g + b;
        cv[u] = f2bf(0.5f * (he + ho));
        dv[u] = f2bf(0.5f * (he - ho));
      }
      *(short8*)&cmn[j * LDSB + seg * 16 + h * 8] = cv;
      *(short8*)&dif[j * LDSB + seg * 16 + h * 8] = dv;
    }
  }
  __syncthreads();

  const int w  = t >> 6, l = t & 63;
  const int lr = l & 15;          // A-row / B,C-col within tile
  const int lk = (l >> 4) * 8;    // k offset within K=32 step
  const int l4 = (l >> 4) * 4;    // C/D row offset
  const f32x4 Z = {0.f, 0.f, 0.f, 0.f};

  // ---------------- Phase C: layer1 of c/d MLPs (M=32,K=128,N=128), gelu -> h1
  {
    const short* cmn = r1;
    const short* dif = r1 + 32 * LDSB;
    short* h1c = r2;
    short* h1d = r2 + 32 * LDSB;
    f32x4 acc[2][2][2];
    #pragma unroll
    for (int a0 = 0; a0 < 2; ++a0)
      #pragma unroll
      for (int a1 = 0; a1 < 2; ++a1)
        #pragma unroll
        for (int a2 = 0; a2 < 2; ++a2) acc[a0][a1][a2] = Z;
    #pragma unroll
    for (int kk = 0; kk < 4; ++kk) {
      short8 av[2][2], bv[2][2];
      #pragma unroll
      for (int mt = 0; mt < 2; ++mt) {
        av[0][mt] = *(const short8*)&cmn[(mt * 16 + lr) * LDSB + kk * 32 + lk];
        av[1][mt] = *(const short8*)&dif[(mt * 16 + lr) * LDSB + kk * 32 + lk];
      }
      #pragma unroll
      for (int ntl = 0; ntl < 2; ++ntl) {
        int nt = w * 2 + ntl;
        bv[0][ntl] = *(const short8*)&pk[PK_CW1 + (kk * 8 + nt) * 512 + l * 8];
        bv[1][ntl] = *(const short8*)&pk[PK_DW1 + (kk * 8 + nt) * 512 + l * 8];
      }
      #pragma unroll
      for (int mat = 0; mat < 2; ++mat)
        #pragma unroll
        for (int mt = 0; mt < 2; ++mt)
          #pragma unroll
          for (int ntl = 0; ntl < 2; ++ntl)
            acc[mat][mt][ntl] = mfma16(av[mat][mt], bv[mat][ntl], acc[mat][mt][ntl]);
    }
    #pragma unroll
    for (int mat = 0; mat < 2; ++mat) {
      const float* bptr = mat ? d_b1 : c_b1;
      short* hp = mat ? h1d : h1c;
      #pragma unroll
      for (int mt = 0; mt < 2; ++mt)
        #pragma unroll
        for (int ntl = 0; ntl < 2; ++ntl) {
          int col = (w * 2 + ntl) * 16 + lr;
          float bias = bptr[col];
          #pragma unroll
          for (int r = 0; r < 4; ++r) {
            int row = mt * 16 + l4 + r;
            hp[row * LDSB + col] = f2bf(gelu_f(acc[mat][mt][ntl][r] + bias));
          }
        }
    }
  }
  __syncthreads();

  // ---------------- Phase C2: layer2 of c/d MLPs, combine into out (in-place in xs)
  {
    const short* h1c = r2;
    const short* h1d = r2 + 32 * LDSB;
    f32x4 acc[2][2][2];
    #pragma unroll
    for (int a0 = 0; a0 < 2; ++a0)
      #pragma unroll
      for (int a1 = 0; a1 < 2; ++a1)
        #pragma unroll
        for (int a2 = 0; a2 < 2; ++a2) acc[a0][a1][a2] = Z;
    #pragma unroll
    for (int kk = 0; kk < 4; ++kk) {
      short8 av[2][2], bv[2][2];
      #pragma unroll
      for (int mt = 0; mt < 2; ++mt) {
        av[0][mt] = *(const short8*)&h1c[(mt * 16 + lr) * LDSB + kk * 32 + lk];
        av[1][mt] = *(const short8*)&h1d[(mt * 16 + lr) * LDSB + kk * 32 + lk];
      }
      #pragma unroll
      for (int ntl = 0; ntl < 2; ++ntl) {
        int nt = w * 2 + ntl;
        bv[0][ntl] = *(const short8*)&pk[PK_CW2 + (kk * 8 + nt) * 512 + l * 8];
        bv[1][ntl] = *(const short8*)&pk[PK_DW2 + (kk * 8 + nt) * 512 + l * 8];
      }
      #pragma unroll
      for (int mat = 0; mat < 2; ++mat)
        #pragma unroll
        for (int mt = 0; mt < 2; ++mt)
          #pragma unroll
          for (int ntl = 0; ntl < 2; ++ntl)
            acc[mat][mt][ntl] = mfma16(av[mat][mt], bv[mat][ntl], acc[mat][mt][ntl]);
    }
    #pragma unroll
    for (int mt = 0; mt < 2; ++mt)
      #pragma unroll
      for (int ntl = 0; ntl < 2; ++ntl) {
        int col = (w * 2 + ntl) * 16 + lr;
        float bc = c_b2[col], bd = d_b2[col];
        #pragma unroll
        for (int r = 0; r < 4; ++r) {
          int j = mt * 16 + l4 + r;
          float uc = acc[0][mt][ntl][r] + bc;
          float ud = acc[1][mt][ntl][r] + bd;
          float ve = xs[(2 * j) * LDSX + col];
          float vo = xs[(2 * j + 1) * LDSX + col];
          xs[(2 * j) * LDSX + col]     = ve + uc + ud;
          xs[(2 * j + 1) * LDSX + col] = vo + uc - ud;
        }
      }
  }
  __syncthreads();

  // ---------------- Phase D: LN(out) -> h2 (bf16, LDS, r2)
  {
    short* h2 = r2;                                // [64][LDSB]
    int row = t >> 2, q = t & 3;                   // 4 threads per row
    float vals[32];
    float s = 0.f, ss = 0.f;
    #pragma unroll
    for (int i = 0; i < 8; ++i) {
      float4 a = *(const float4*)&xs[row * LDSX + q * 32 + 4 * i];
      vals[4*i+0]=a.x; vals[4*i+1]=a.y; vals[4*i+2]=a.z; vals[4*i+3]=a.w;
      s  += a.x + a.y + a.z + a.w;
      ss += a.x*a.x + a.y*a.y + a.z*a.z + a.w*a.w;
    }
    s  += __shfl_xor(s, 1);  s  += __shfl_xor(s, 2);
    ss += __shfl_xor(ss, 1); ss += __shfl_xor(ss, 2);
    float mu = s * (1.0f / 128.0f);
    float rs = rsqrtf(ss * (1.0f / 128.0f) - mu * mu + 1e-5f);
    #pragma unroll
    for (int h = 0; h < 4; ++h) {
      short8 hv;
      #pragma unroll
      for (int u = 0; u < 8; ++u) {
        int c = q * 32 + h * 8 + u;
        hv[u] = f2bf((vals[h * 8 + u] - mu) * rs * ln_g[c] + ln_b[c]);
      }
      *(short8*)&h2[row * LDSB + q * 32 + h * 8] = hv;
    }
  }
  __syncthreads();

  // ---------------- Phase E: f MLP (M=64,K=128 -> H=256 in 2 halves -> 128), residual, store
  {
    const short* h2 = r2;
    short* hf1 = r1;                               // [64][LDSB] current half
    f32x4 uacc[4][2];
    #pragma unroll
    for (int a0 = 0; a0 < 4; ++a0) { uacc[a0][0] = Z; uacc[a0][1] = Z; }

    #pragma unroll
    for (int hf = 0; hf < 2; ++hf) {
      f32x4 acc1[4][2];
      #pragma unroll
      for (int a0 = 0; a0 < 4; ++a0) { acc1[a0][0] = Z; acc1[a0][1] = Z; }
      #pragma unroll
      for (int kk = 0; kk < 4; ++kk) {
        short8 av[4], bv[2];
        #pragma unroll
        for (int mt = 0; mt < 4; ++mt)
          av[mt] = *(const short8*)&h2[(mt * 16 + lr) * LDSB + kk * 32 + lk];
        #pragma unroll
        for (int ntl = 0; ntl < 2; ++ntl) {
          int ntg = hf * 8 + w * 2 + ntl;
          bv[ntl] = *(const short8*)&pk[PK_FW1 + (kk * 16 + ntg) * 512 + l * 8];
        }
        #pragma unroll
        for (int mt = 0; mt < 4; ++mt)
          #pragma unroll
          for (int ntl = 0; ntl < 2; ++ntl)
            acc1[mt][ntl] = mfma16(av[mt], bv[ntl], acc1[mt][ntl]);
      }
      #pragma unroll
      for (int mt = 0; mt < 4; ++mt)
        #pragma unroll
        for (int ntl = 0; ntl < 2; ++ntl) {
          int coll = (w * 2 + ntl) * 16 + lr;
          float bias = f_b1[hf * 128 + coll];
          #pragma unroll
          for (int r = 0; r < 4; ++r) {
            int row = mt * 16 + l4 + r;
            hf1[row * LDSB + coll] = f2bf(gelu_f(acc1[mt][ntl][r] + bias));
          }
        }
      __syncthreads();
      #pragma unroll
      for (int kk = 0; kk < 4; ++kk) {
        short8 av[4], bv[2];
        #pragma unroll
        for (int mt = 0; mt < 4; ++mt)
          av[mt] = *(const short8*)&hf1[(mt * 16 + lr) * LDSB + kk * 32 + lk];
        #pragma unroll
        for (int ntl = 0; ntl < 2; ++ntl)
          bv[ntl] = *(const short8*)&pk[PK_FW2 + ((hf * 4 + kk) * 8 + w * 2 + ntl) * 512 + l * 8];
        #pragma unroll
        for (int mt = 0; mt < 4; ++mt)
          #pragma unroll
          for (int ntl = 0; ntl < 2; ++ntl)
            uacc[mt][ntl] = mfma16(av[mt], bv[ntl], uacc[mt][ntl]);
      }
      __syncthreads();                             // protect hf1 before next half's overwrite
    }

    float* og = out + base;
    #pragma unroll
    for (int mt = 0; mt < 4; ++mt)
      #pragma unroll
      for (int ntl = 0; ntl < 2; ++ntl) {
        int col = (w * 2 + ntl) * 16 + lr;
        float bias = f_b2[col];
        #pragma unroll
        for (int r = 0; r < 4; ++r) {
          int row = mt * 16 + l4 + r;
          og[row * 128 + col] = xs[row * LDSX + col] + uacc[mt][ntl][r] + bias;
        }
      }
  }
}

extern "C" void kernel_launch(void* const* d_in, const int* in_sizes, int n_in,
                              void* d_out, int out_size, void* d_ws, size_t ws_size,
                              hipStream_t stream) {
  (void)in_sizes; (void)n_in; (void)out_size; (void)ws_size;
  const float* x    = (const float*)d_in[0];
  const float* ln_g = (const float*)d_in[1];
  const float* ln_b = (const float*)d_in[2];
  const float* cW1  = (const float*)d_in[3];
  const float* c_b1 = (const float*)d_in[4];
  const float* cW2  = (const float*)d_in[5];
  const float* c_b2 = (const float*)d_in[6];
  const float* dW1  = (const float*)d_in[7];
  const float* d_b1 = (const float*)d_in[8];
  const float* dW2  = (const float*)d_in[9];
  const float* d_b2 = (const float*)d_in[10];
  const float* fW1  = (const float*)d_in[11];
  const float* f_b1 = (const float*)d_in[12];
  const float* fW2  = (const float*)d_in[13];
  const float* f_b2 = (const float*)d_in[14];
  short* pk  = (short*)d_ws;                   // 131072 bf16 = 256 KB
  float* out = (float*)d_out;

  hipFuncSetAttribute((const void*)hemi_fused_k,
                      hipFuncAttributeMaxDynamicSharedMemorySize, SMEM_BYTES);

  pack_weights_k<<<64, 256, 0, stream>>>(cW1, cW2, dW1, dW2, fW1, fW2, pk);
  hemi_fused_k<<<8192, 256, SMEM_BYTES, stream>>>(x, ln_g, ln_b, c_b1, c_b2,
                                                  d_b1, d_b2, f_b1, f_b2, pk, out);
}

// Round 3
// 322.155 us; speedup vs baseline: 1.1386x; 1.1386x over previous
//
#include <hip/hip_runtime.h>

using short8 = __attribute__((ext_vector_type(8))) short;
using bf16x4 = __attribute__((ext_vector_type(4))) short;
using f32x4  = __attribute__((ext_vector_type(4))) float;

#define LB 136                      // bf16 row stride (shorts) = 272 B (16B-aligned rows)
#define P2_OFF (2*32*LB)            // after cmn[32][LB]+dif[32][LB]
#define P3_OFF (P2_OFF + 64*LB)
#define SM_SHORTS (P3_OFF + 64*LB)  // 26112 shorts = 52224 B -> 3 blocks/CU

#define PK_CW1 0
#define PK_CW2 16384
#define PK_DW1 32768
#define PK_DW2 49152
#define PK_FW1 65536
#define PK_FW2 98304

__device__ __forceinline__ short f2bf(float f) {
  __bf16 h = (__bf16)f;                    // RTNE, lowers to hw cvt on gfx950
  return __builtin_bit_cast(short, h);
}
__device__ __forceinline__ float bf2f(short s) {
  unsigned u = ((unsigned)(unsigned short)s) << 16;
  return __builtin_bit_cast(float, u);
}

__device__ __forceinline__ float gelu_f(float x) {
  // tanh-form GELU via 2^u: t = 1 - 2/(2^(u*log2e)+1); max |err| vs erf-GELU ~3e-3
  float x2 = x * x;
  float u2 = x * (2.302118142f + 0.103178252f * x2);  // 1.59577*(x+0.044715x^3)*log2(e)
  float e  = __builtin_amdgcn_exp2f(u2);
  float t  = 1.0f - 2.0f / (e + 1.0f);
  return 0.5f * x * (1.0f + t);
}

__device__ __forceinline__ f32x4 mfma16(short8 a, short8 b, f32x4 c) {
  return __builtin_amdgcn_mfma_f32_16x16x32_bf16(a, b, c, 0, 0, 0);
}

// Pre-pack all weights into fragment-major bf16 (unchanged layout):
// packed[fb*512 + lane*8 + j] = bf16(W[kk*32 + (lane>>4)*8 + j][nt*16 + (lane&15)])
__global__ void pack_weights_k(const float* __restrict__ cW1, const float* __restrict__ cW2,
                               const float* __restrict__ dW1, const float* __restrict__ dW2,
                               const float* __restrict__ fW1, const float* __restrict__ fW2,
                               short* __restrict__ pk) {
  int fid  = blockIdx.x * 256 + threadIdx.x;
  int lane = fid & 63;
  int fbg  = fid >> 6;
  const float* W; int N; int fb;
  if (fbg < 32)       { W = cW1; N = 128; fb = fbg; }
  else if (fbg < 64)  { W = cW2; N = 128; fb = fbg - 32; }
  else if (fbg < 96)  { W = dW1; N = 128; fb = fbg - 64; }
  else if (fbg < 128) { W = dW2; N = 128; fb = fbg - 96; }
  else if (fbg < 192) { W = fW1; N = 256; fb = fbg - 128; }
  else                { W = fW2; N = 128; fb = fbg - 192; }
  int nt = fb % (N >> 4);
  int kk = fb / (N >> 4);
  int row0 = kk * 32 + (lane >> 4) * 8;
  int col  = nt * 16 + (lane & 15);
  short8 v;
  #pragma unroll
  for (int j = 0; j < 8; ++j) v[j] = f2bf(W[(row0 + j) * N + col]);
  *(short8*)&pk[fbg * 512 + lane * 8] = v;
}

__global__ __launch_bounds__(256, 3)
void hemi_fused_k(const float* __restrict__ x,
                  const float* __restrict__ ln_g, const float* __restrict__ ln_b,
                  const float* __restrict__ c_b1, const float* __restrict__ c_b2,
                  const float* __restrict__ d_b1, const float* __restrict__ d_b2,
                  const float* __restrict__ f_b1, const float* __restrict__ f_b2,
                  const short* __restrict__ pk,
                  float* __restrict__ out) {
  __shared__ short sm[SM_SHORTS];
  short* P1 = sm;            // cmn rows[0,32) + dif rows[32,64); later h1c/h1d; later ucU/udU
  short* P2 = sm + P2_OFF;   // h2[64][LB]
  short* P3 = sm + P3_OFF;   // hf1[64][LB]; later updU[64][LB]

  const int t = threadIdx.x;
  const int w = t >> 6, l = t & 63;
  const int half = l >> 5;          // 0: even row of pair, 1: odd row
  const int m32  = l & 31;          // 4-col chunk index
  const size_t base = (size_t)blockIdx.x * 8192;   // (b,t) tile: 64 rows x 128 cols

  // ---------------- Phase A: coalesced load x -> regs; per-row LN stats via shuffles
  // thread holds rows {2w + half + 8i : i=0..7}, cols [4*m32, 4*m32+4)
  float xv[8][4];
  float mu[8], rs[8];
  {
    const float4* xg = (const float4*)(x + base);
    #pragma unroll
    for (int i = 0; i < 8; ++i) {
      float4 a = xg[t + 256 * i];
      xv[i][0] = a.x; xv[i][1] = a.y; xv[i][2] = a.z; xv[i][3] = a.w;
      float s = a.x + a.y + a.z + a.w;
      float q = a.x * a.x + a.y * a.y + a.z * a.z + a.w * a.w;
      #pragma unroll
      for (int m = 1; m <= 16; m <<= 1) { s += __shfl_xor(s, m); q += __shfl_xor(q, m); }
      mu[i] = s * (1.0f / 128.0f);
      rs[i] = rsqrtf(q * (1.0f / 128.0f) - mu[i] * mu[i] + 1e-5f);
    }
  }

  float gg[4], bb[4];
  {
    float4 g4 = ((const float4*)ln_g)[m32];
    float4 b4 = ((const float4*)ln_b)[m32];
    gg[0]=g4.x; gg[1]=g4.y; gg[2]=g4.z; gg[3]=g4.w;
    bb[0]=b4.x; bb[1]=b4.y; bb[2]=b4.z; bb[3]=b4.w;
  }

  // ---------------- Phase B: LN + pair exchange (shfl_xor 32) -> cmn/dif bf16 in LDS
  #pragma unroll
  for (int i = 0; i < 8; ++i) {
    int j = w + 4 * i;               // pair index 0..31
    float hv[4];
    #pragma unroll
    for (int u = 0; u < 4; ++u) hv[u] = (xv[i][u] - mu[i]) * rs[i] * gg[u] + bb[u];
    bf16x4 wv;
    #pragma unroll
    for (int u = 0; u < 4; ++u) {
      float o = __shfl_xor(hv[u], 32);     // partner row's LN value, same col
      float v = half ? 0.5f * (o - hv[u])  // dif = 0.5*(h_even - h_odd)
                     : 0.5f * (hv[u] + o); // cmn
      wv[u] = f2bf(v);
    }
    *(bf16x4*)&P1[(half * 32 + j) * LB + m32 * 4] = wv;
  }
  __syncthreads();

  const int lr  = l & 15;
  const int lk  = (l >> 4) * 8;
  const int l4n = (l >> 4) * 4;
  const f32x4 Z = {0.f, 0.f, 0.f, 0.f};

  // ---------------- Phase C: layer1 of c/d MLPs (M=32,K=128,N=128), gelu -> h1 (overwrites P1)
  {
    f32x4 acc[2][2][2];
    #pragma unroll
    for (int a0 = 0; a0 < 2; ++a0)
      #pragma unroll
      for (int a1 = 0; a1 < 2; ++a1)
        #pragma unroll
        for (int a2 = 0; a2 < 2; ++a2) acc[a0][a1][a2] = Z;
    #pragma unroll
    for (int kk = 0; kk < 4; ++kk) {
      short8 av[2][2], bv[2][2];
      #pragma unroll
      for (int mt = 0; mt < 2; ++mt) {
        av[0][mt] = *(const short8*)&P1[(     mt * 16 + lr) * LB + kk * 32 + lk];
        av[1][mt] = *(const short8*)&P1[(32 + mt * 16 + lr) * LB + kk * 32 + lk];
      }
      #pragma unroll
      for (int ntl = 0; ntl < 2; ++ntl) {
        int nt = w * 2 + ntl;
        bv[0][ntl] = *(const short8*)&pk[PK_CW1 + (kk * 8 + nt) * 512 + l * 8];
        bv[1][ntl] = *(const short8*)&pk[PK_DW1 + (kk * 8 + nt) * 512 + l * 8];
      }
      #pragma unroll
      for (int mat = 0; mat < 2; ++mat)
        #pragma unroll
        for (int mt = 0; mt < 2; ++mt)
          #pragma unroll
          for (int ntl = 0; ntl < 2; ++ntl)
            acc[mat][mt][ntl] = mfma16(av[mat][mt], bv[mat][ntl], acc[mat][mt][ntl]);
    }
    __syncthreads();                       // all cmn/dif reads done -> safe to overwrite
    #pragma unroll
    for (int mat = 0; mat < 2; ++mat) {
      const float* bp = mat ? d_b1 : c_b1;
      #pragma unroll
      for (int mt = 0; mt < 2; ++mt)
        #pragma unroll
        for (int ntl = 0; ntl < 2; ++ntl) {
          int col = (w * 2 + ntl) * 16 + lr;
          float bias = bp[col];
          #pragma unroll
          for (int r = 0; r < 4; ++r)
            P1[(mat * 32 + mt * 16 + l4n + r) * LB + col] =
                f2bf(gelu_f(acc[mat][mt][ntl][r] + bias));
        }
    }
  }
  __syncthreads();

  // ---------------- Phase C2: layer2 of c/d MLPs -> ucU/udU bf16 (overwrites P1)
  {
    f32x4 acc[2][2][2];
    #pragma unroll
    for (int a0 = 0; a0 < 2; ++a0)
      #pragma unroll
      for (int a1 = 0; a1 < 2; ++a1)
        #pragma unroll
        for (int a2 = 0; a2 < 2; ++a2) acc[a0][a1][a2] = Z;
    #pragma unroll
    for (int kk = 0; kk < 4; ++kk) {
      short8 av[2][2], bv[2][2];
      #pragma unroll
      for (int mt = 0; mt < 2; ++mt) {
        av[0][mt] = *(const short8*)&P1[(     mt * 16 + lr) * LB + kk * 32 + lk];
        av[1][mt] = *(const short8*)&P1[(32 + mt * 16 + lr) * LB + kk * 32 + lk];
      }
      #pragma unroll
      for (int ntl = 0; ntl < 2; ++ntl) {
        int nt = w * 2 + ntl;
        bv[0][ntl] = *(const short8*)&pk[PK_CW2 + (kk * 8 + nt) * 512 + l * 8];
        bv[1][ntl] = *(const short8*)&pk[PK_DW2 + (kk * 8 + nt) * 512 + l * 8];
      }
      #pragma unroll
      for (int mat = 0; mat < 2; ++mat)
        #pragma unroll
        for (int mt = 0; mt < 2; ++mt)
          #pragma unroll
          for (int ntl = 0; ntl < 2; ++ntl)
            acc[mat][mt][ntl] = mfma16(av[mat][mt], bv[mat][ntl], acc[mat][mt][ntl]);
    }
    __syncthreads();                       // all h1 reads done -> safe to overwrite
    #pragma unroll
    for (int mt = 0; mt < 2; ++mt)
      #pragma unroll
      for (int ntl = 0; ntl < 2; ++ntl) {
        int col = (w * 2 + ntl) * 16 + lr;
        float bc = c_b2[col], bd = d_b2[col];
        #pragma unroll
        for (int r = 0; r < 4; ++r) {
          int j = mt * 16 + l4n + r;
          P1[      j * LB + col] = f2bf(acc[0][mt][ntl][r] + bc);   // ucU
          P1[(32 + j) * LB + col] = f2bf(acc[1][mt][ntl][r] + bd);  // udU
        }
      }
  }
  __syncthreads();

  // ---------------- Phase R+D: out = x + uc±ud (regs); LN(out) stats; h2 -> P2
  #pragma unroll
  for (int i = 0; i < 8; ++i) {
    int j = w + 4 * i;
    bf16x4 uc4 = *(const bf16x4*)&P1[      j * LB + m32 * 4];
    bf16x4 ud4 = *(const bf16x4*)&P1[(32 + j) * LB + m32 * 4];
    float s = 0.f, q = 0.f;
    #pragma unroll
    for (int u = 0; u < 4; ++u) {
      float uc = bf2f(uc4[u]), ud = bf2f(ud4[u]);
      float o = xv[i][u] + (half ? (uc - ud) : (uc + ud));
      xv[i][u] = o;                       // xv now holds `out`
      s += o; q += o * o;
    }
    #pragma unroll
    for (int m = 1; m <= 16; m <<= 1) { s += __shfl_xor(s, m); q += __shfl_xor(q, m); }
    mu[i] = s * (1.0f / 128.0f);
    rs[i] = rsqrtf(q * (1.0f / 128.0f) - mu[i] * mu[i] + 1e-5f);
  }
  #pragma unroll
  for (int i = 0; i < 8; ++i) {
    int row = 2 * w + half + 8 * i;
    bf16x4 hv;
    #pragma unroll
    for (int u = 0; u < 4; ++u)
      hv[u] = f2bf((xv[i][u] - mu[i]) * rs[i] * gg[u] + bb[u]);
    *(bf16x4*)&P2[row * LB + m32 * 4] = hv;
  }
  __syncthreads();

  // ---------------- Phase E: f MLP (M=64, 128 -> 256 (2 halves) -> 128)
  f32x4 uacc[4][2];
  #pragma unroll
  for (int a0 = 0; a0 < 4; ++a0) { uacc[a0][0] = Z; uacc[a0][1] = Z; }
  #pragma unroll
  for (int hf = 0; hf < 2; ++hf) {
    f32x4 acc1[4][2];
    #pragma unroll
    for (int a0 = 0; a0 < 4; ++a0) { acc1[a0][0] = Z; acc1[a0][1] = Z; }
    #pragma unroll
    for (int kk = 0; kk < 4; ++kk) {
      short8 av[4], bv[2];
      #pragma unroll
      for (int mt = 0; mt < 4; ++mt)
        av[mt] = *(const short8*)&P2[(mt * 16 + lr) * LB + kk * 32 + lk];
      #pragma unroll
      for (int ntl = 0; ntl < 2; ++ntl)
        bv[ntl] = *(const short8*)&pk[PK_FW1 + (kk * 16 + hf * 8 + w * 2 + ntl) * 512 + l * 8];
      #pragma unroll
      for (int mt = 0; mt < 4; ++mt)
        #pragma unroll
        for (int ntl = 0; ntl < 2; ++ntl)
          acc1[mt][ntl] = mfma16(av[mt], bv[ntl], acc1[mt][ntl]);
    }
    if (hf) __syncthreads();              // hf0's layer2 reads of P3 must finish first
    #pragma unroll
    for (int mt = 0; mt < 4; ++mt)
      #pragma unroll
      for (int ntl = 0; ntl < 2; ++ntl) {
        int col = (w * 2 + ntl) * 16 + lr;
        float bias = f_b1[hf * 128 + col];
        #pragma unroll
        for (int r = 0; r < 4; ++r)
          P3[(mt * 16 + l4n + r) * LB + col] = f2bf(gelu_f(acc1[mt][ntl][r] + bias));
      }
    __syncthreads();
    #pragma unroll
    for (int kk = 0; kk < 4; ++kk) {
      short8 av[4], bv[2];
      #pragma unroll
      for (int mt = 0; mt < 4; ++mt)
        av[mt] = *(const short8*)&P3[(mt * 16 + lr) * LB + kk * 32 + lk];
      #pragma unroll
      for (int ntl = 0; ntl < 2; ++ntl)
        bv[ntl] = *(const short8*)&pk[PK_FW2 + ((hf * 4 + kk) * 8 + w * 2 + ntl) * 512 + l * 8];
      #pragma unroll
      for (int mt = 0; mt < 4; ++mt)
        #pragma unroll
        for (int ntl = 0; ntl < 2; ++ntl)
          uacc[mt][ntl] = mfma16(av[mt], bv[ntl], uacc[mt][ntl]);
    }
  }
  __syncthreads();                        // hf1's layer2 reads done -> safe to overwrite P3

  // ---------------- Phase F: upd -> P3 (bf16); final out = out_reg + upd, coalesced store
  #pragma unroll
  for (int mt = 0; mt < 4; ++mt)
    #pragma unroll
    for (int ntl = 0; ntl < 2; ++ntl) {
      int col = (w * 2 + ntl) * 16 + lr;
      float bias = f_b2[col];
      #pragma unroll
      for (int r = 0; r < 4; ++r)
        P3[(mt * 16 + l4n + r) * LB + col] = f2bf(uacc[mt][ntl][r] + bias);
    }
  __syncthreads();

  {
    float4* og = (float4*)(out + base);
    #pragma unroll
    for (int i = 0; i < 8; ++i) {
      int row = 2 * w + half + 8 * i;
      bf16x4 u4 = *(const bf16x4*)&P3[row * LB + m32 * 4];
      float4 a;
      a.x = xv[i][0] + bf2f(u4[0]);
      a.y = xv[i][1] + bf2f(u4[1]);
      a.z = xv[i][2] + bf2f(u4[2]);
      a.w = xv[i][3] + bf2f(u4[3]);
      og[t + 256 * i] = a;
    }
  }
}

extern "C" void kernel_launch(void* const* d_in, const int* in_sizes, int n_in,
                              void* d_out, int out_size, void* d_ws, size_t ws_size,
                              hipStream_t stream) {
  (void)in_sizes; (void)n_in; (void)out_size; (void)ws_size;
  const float* x    = (const float*)d_in[0];
  const float* ln_g = (const float*)d_in[1];
  const float* ln_b = (const float*)d_in[2];
  const float* cW1  = (const float*)d_in[3];
  const float* c_b1 = (const float*)d_in[4];
  const float* cW2  = (const float*)d_in[5];
  const float* c_b2 = (const float*)d_in[6];
  const float* dW1  = (const float*)d_in[7];
  const float* d_b1 = (const float*)d_in[8];
  const float* dW2  = (const float*)d_in[9];
  const float* d_b2 = (const float*)d_in[10];
  const float* fW1  = (const float*)d_in[11];
  const float* f_b1 = (const float*)d_in[12];
  const float* fW2  = (const float*)d_in[13];
  const float* f_b2 = (const float*)d_in[14];
  short* pk  = (short*)d_ws;               // 131072 bf16 = 256 KB
  float* out = (float*)d_out;

  pack_weights_k<<<64, 256, 0, stream>>>(cW1, cW2, dW1, dW2, fW1, fW2, pk);
  hemi_fused_k<<<8192, 256, 0, stream>>>(x, ln_g, ln_b, c_b1, c_b2,
                                         d_b1, d_b2, f_b1, f_b2, pk, out);
}